// Round 8
// baseline (87.078 us; speedup 1.0000x reference)
//
#include <hip/hip_runtime.h>

// IDW, POWER=2.0 -> w = 1/d2 (sqrt cancels). out = sum(w*v)/sum(w).
// B=2, P=131072, S=512.
// R13: R11 vs R12 isolated the lever: pts/us/CU = 43.9 (GPT=8) vs ~25
//   (GPT=4, even with identical 512-inst unroll window) -> efficiency comes
//   from 8 quads per 3 ds_reads / per chunk-stall (amortization), not from
//   the scheduling window. R11's 41% residual stall ~ trans issue (~16cyc
//   wave64 rcp x8/chunk) + lgkm waits at 1 wave/SIMD -- both hideable by a
//   second wave per SIMD.
//   GPT=8 point-parallelism only makes 128 blocks -> fill the chip by
//   splitting the STATION axis (partials additive): NSPLIT=4 -> 512 blocks
//   (2/CU, 2 waves/SIMD), each doing 128 stations x 2048 points with the
//   exact R11 inner loop. Tiny combine kernel (16MB read, 1MB write ~3us)
//   reduces 4 partials + divides. Workspace >=256MiB (poison fill proves);
//   partials = 8MB, every slot written before read -> poison harmless, no
//   zeroing, no atomics. Station weights bit-identical; only final sum
//   order changes (ulp-scale).
//   Arithmetic: chip VALU work 13.65us @100% duty; @59% -> 23us; with 2nd
//   wave hiding trans/LDS -> predict main 14-18us, total 62-71.
// Math unchanged since R6: 4-way rcp-combine, 31 VALU + 1 trans per quad;
//   EPS2 folded into the d2 fma chain (exact at d2==0: w -> 1/EPS^2).

#define BLOCK 256
#define GPT 8
#define NSPLIT 4
#define S_TOT 512
#define S_SUB (S_TOT / NSPLIT)  // 128 stations per block

__device__ __forceinline__ void quad_op(float gx, float gy, float& ws, float& vs,
                                        const float4& f0, const float4& f1,
                                        const float4& f2) {
    constexpr float EPS  = 1.1920928955078125e-07f;
    constexpr float EPS2 = EPS * EPS;
    const float dxa = gx - f0.x, dya = gy - f0.y;
    const float a = fmaf(dxa, dxa, fmaf(dya, dya, EPS2));
    const float dxb = gx - f0.w, dyb = gy - f1.x;
    const float bq = fmaf(dxb, dxb, fmaf(dyb, dyb, EPS2));
    const float dxc = gx - f1.z, dyc = gy - f1.w;
    const float c = fmaf(dxc, dxc, fmaf(dyc, dyc, EPS2));
    const float dxd = gx - f2.y, dyd = gy - f2.z;
    const float d = fmaf(dxd, dxd, fmaf(dyd, dyd, EPS2));
    const float pab = a * bq, pcd = c * d;
    const float sab = a + bq, scd = c + d;
    const float nab = fmaf(f1.y, a, f0.z * bq);  // vB*a + vA*b
    const float ncd = fmaf(f2.w, c, f2.x * d);   // vD*c + vC*d
    const float r = __builtin_amdgcn_rcpf(pab * pcd);
    ws = fmaf(fmaf(sab, pcd, scd * pab), r, ws);
    vs = fmaf(fmaf(nab, pcd, ncd * pab), r, vs);
}

// Main: each block = (point-tile x, batch y, station-quarter z).
// Writes per-point float2 {ws, vs} partials to ws buffer.
__global__ __launch_bounds__(BLOCK) void idw_main(
    const float* __restrict__ station_coords,  // (B, S, 2)
    const float* __restrict__ station_values,  // (B, S)
    const float* __restrict__ grid_points,     // (B, P, 2)
    float2* __restrict__ partial,              // (NSPLIT, B, P) float2
    int P, int S) {

    __shared__ float st[S_SUB * 3];  // packed {x,y,v}, 1536 B

    const int b = blockIdx.y;
    const int z = blockIdx.z;
    const float2* __restrict__ sc2 =
        (const float2*)station_coords + (size_t)b * S + z * S_SUB;
    const float* __restrict__ svb = station_values + (size_t)b * S + z * S_SUB;

    if (threadIdx.x < S_SUB) {
        const int i = threadIdx.x;
        const float2 c = sc2[i];
        st[3 * i + 0] = c.x;
        st[3 * i + 1] = c.y;
        st[3 * i + 2] = svb[i];
    }
    __syncthreads();

    const int tid = blockIdx.x * BLOCK + threadIdx.x;
    const float4* __restrict__ gp4 = (const float4*)grid_points + (size_t)b * (P / 2);
    const float4 ga = gp4[4 * tid + 0];
    const float4 gb = gp4[4 * tid + 1];
    const float4 gc = gp4[4 * tid + 2];
    const float4 gd = gp4[4 * tid + 3];
    const float gx0 = ga.x, gy0 = ga.y, gx1 = ga.z, gy1 = ga.w;
    const float gx2 = gb.x, gy2 = gb.y, gx3 = gb.z, gy3 = gb.w;
    const float gx4 = gc.x, gy4 = gc.y, gx5 = gc.z, gy5 = gc.w;
    const float gx6 = gd.x, gy6 = gd.y, gx7 = gd.z, gy7 = gd.w;

    float ws0 = 0.0f, vs0 = 0.0f, ws1 = 0.0f, vs1 = 0.0f;
    float ws2 = 0.0f, vs2 = 0.0f, ws3 = 0.0f, vs3 = 0.0f;
    float ws4 = 0.0f, vs4 = 0.0f, ws5 = 0.0f, vs5 = 0.0f;
    float ws6 = 0.0f, vs6 = 0.0f, ws7 = 0.0f, vs7 = 0.0f;

    const float4* __restrict__ st4 = (const float4*)st;

    // layout: f0 = Ax Ay Av Bx | f1 = By Bv Cx Cy | f2 = Cv Dx Dy Dv
#pragma unroll 2
    for (int k = 0; k < S_SUB / 4; ++k) {
        const float4 f0 = st4[3 * k + 0];
        const float4 f1 = st4[3 * k + 1];
        const float4 f2 = st4[3 * k + 2];
        quad_op(gx0, gy0, ws0, vs0, f0, f1, f2);
        quad_op(gx1, gy1, ws1, vs1, f0, f1, f2);
        quad_op(gx2, gy2, ws2, vs2, f0, f1, f2);
        quad_op(gx3, gy3, ws3, vs3, f0, f1, f2);
        quad_op(gx4, gy4, ws4, vs4, f0, f1, f2);
        quad_op(gx5, gy5, ws5, vs5, f0, f1, f2);
        quad_op(gx6, gy6, ws6, vs6, f0, f1, f2);
        quad_op(gx7, gy7, ws7, vs7, f0, f1, f2);
    }

    // Points p0 = 8*tid .. 8*tid+7; float2 per point -> 4 float4 stores.
    float4* __restrict__ pb4 =
        (float4*)(partial + ((size_t)(z * 2 + b)) * P);
    pb4[4 * tid + 0] = make_float4(ws0, vs0, ws1, vs1);
    pb4[4 * tid + 1] = make_float4(ws2, vs2, ws3, vs3);
    pb4[4 * tid + 2] = make_float4(ws4, vs4, ws5, vs5);
    pb4[4 * tid + 3] = make_float4(ws6, vs6, ws7, vs7);
}

// Combine: out = (sum_z vs) / (sum_z ws). 4 points/thread.
__global__ __launch_bounds__(256) void idw_combine(
    const float2* __restrict__ partial, float* __restrict__ out, int P) {
    const int gid = blockIdx.x * 256 + threadIdx.x;
    const int pp0 = gid * 4;              // flat point index over (B, P)
    const int b = pp0 >> 17;              // P = 131072 = 2^17
    const int p0 = pp0 & (131072 - 1);

    float wa = 0.f, va = 0.f, wb = 0.f, vb = 0.f, wc = 0.f, vc = 0.f, wd = 0.f, vd = 0.f;
#pragma unroll
    for (int z = 0; z < NSPLIT; ++z) {
        const float4* __restrict__ src =
            (const float4*)(partial + ((size_t)(z * 2 + b)) * P);
        const float4 lo = src[p0 / 2 + 0];   // pts p0, p0+1
        const float4 hi = src[p0 / 2 + 1];   // pts p0+2, p0+3
        wa += lo.x; va += lo.y; wb += lo.z; vb += lo.w;
        wc += hi.x; vc += hi.y; wd += hi.z; vd += hi.w;
    }
    ((float4*)out)[((size_t)b * P + p0) / 4] =
        make_float4(va / wa, vb / wb, vc / wc, vd / wd);
}

// Fallback (ws too small; should never trigger -- poison fill shows >=256MiB):
// R12 single-kernel full-chip path.
__global__ __launch_bounds__(BLOCK) void idw_single(
    const float* __restrict__ station_coords, const float* __restrict__ station_values,
    const float* __restrict__ grid_points, float* __restrict__ out, int P, int S) {
    __shared__ float st[S_TOT * 3];
    const int b = blockIdx.y;
    const float2* __restrict__ sc2 = (const float2*)station_coords + (size_t)b * S;
    const float* __restrict__ svb = station_values + (size_t)b * S;
    for (int i = threadIdx.x; i < S; i += BLOCK) {
        const float2 c = sc2[i];
        st[3 * i + 0] = c.x; st[3 * i + 1] = c.y; st[3 * i + 2] = svb[i];
    }
    __syncthreads();
    const int tid = blockIdx.x * BLOCK + threadIdx.x;
    const float4* __restrict__ gp4 = (const float4*)grid_points + (size_t)b * (P / 2);
    const float4 ga = gp4[2 * tid + 0];
    const float4 gb = gp4[2 * tid + 1];
    float ws0 = 0, vs0 = 0, ws1 = 0, vs1 = 0, ws2 = 0, vs2 = 0, ws3 = 0, vs3 = 0;
    const float4* __restrict__ st4 = (const float4*)st;
#pragma unroll 4
    for (int k = 0; k < S_TOT / 4; ++k) {
        const float4 f0 = st4[3 * k + 0];
        const float4 f1 = st4[3 * k + 1];
        const float4 f2 = st4[3 * k + 2];
        quad_op(ga.x, ga.y, ws0, vs0, f0, f1, f2);
        quad_op(ga.z, ga.w, ws1, vs1, f0, f1, f2);
        quad_op(gb.x, gb.y, ws2, vs2, f0, f1, f2);
        quad_op(gb.z, gb.w, ws3, vs3, f0, f1, f2);
    }
    ((float4*)out)[(size_t)b * (P / 4) + tid] =
        make_float4(vs0 / ws0, vs1 / ws1, vs2 / ws2, vs3 / ws3);
}

extern "C" void kernel_launch(void* const* d_in, const int* in_sizes, int n_in,
                              void* d_out, int out_size, void* d_ws, size_t ws_size,
                              hipStream_t stream) {
    const float* station_coords = (const float*)d_in[0];
    const float* station_values = (const float*)d_in[1];
    const float* grid_points    = (const float*)d_in[2];
    float* out = (float*)d_out;

    const int B = 2;
    const int S = in_sizes[1] / B;   // 512
    const int P = out_size / B;      // 131072

    const size_t need = (size_t)NSPLIT * B * P * sizeof(float2);  // 8 MB
    if (ws_size >= need && d_ws != nullptr) {
        float2* partial = (float2*)d_ws;
        dim3 grid(P / (BLOCK * GPT), B, NSPLIT);  // 64 x 2 x 4 = 512 blocks
        idw_main<<<grid, dim3(BLOCK), 0, stream>>>(
            station_coords, station_values, grid_points, partial, P, S);
        dim3 cgrid((B * P) / (256 * 4));          // 256 blocks
        idw_combine<<<cgrid, dim3(256), 0, stream>>>(partial, out, P);
    } else {
        dim3 grid(P / (BLOCK * 4), B);
        idw_single<<<grid, dim3(BLOCK), 0, stream>>>(
            station_coords, station_values, grid_points, out, P, S);
    }
}